// Round 7
// baseline (214.620 us; speedup 1.0000x reference)
//
#include <hip/hip_runtime.h>
#include <math.h>

#define TT 2
#define CH 128
#define HH 96
#define WW 96
#define HWS 9216            // H*W
#define QTOT 18432          // T*H*W
#define QC (QTOT*CH)
#define HD 32
#define KTOP 16
#define SCALE 0.17677669529663687f  // 32^-0.5

#define SEG 16              // queries per attn block (one row segment)
#define PR 8                // patch rows
#define PC 23               // patch cols
#define PSTRIDE 36          // floats per patch pixel in LDS

// wbuf layout (bf16): wq_hi @0, wq_lo @16384, wk_hi @32768, wk_lo @49152,
//                     wv_hi @65536, proj_hi @81920   (each 128x128, [o][c])
#define WB_QK(sel) ((sel) * 32768)
#define WB_V 65536
#define WB_P 81920

typedef __attribute__((ext_vector_type(8))) short short8;
typedef __attribute__((ext_vector_type(4))) float floatx4;

__device__ __forceinline__ unsigned short f2bf(float f) {
    union { float f; unsigned u; } x; x.f = f;
    unsigned r = x.u + 0x7fffu + ((x.u >> 16) & 1u);
    return (unsigned short)(r >> 16);
}
__device__ __forceinline__ float bf2f(unsigned short h) {
    return __uint_as_float(((unsigned)h) << 16);
}

__device__ __forceinline__ int refl(int x, int n) {
    x = x < 0 ? -x : x;
    return x >= n ? 2 * (n - 1) - x : x;
}

// ------ one-shot weight conversion: fp32 [o][c] -> bf16 hi (+lo for q,k) ----------
__global__ __launch_bounds__(256) void wprep(
    const float* __restrict__ wq, const float* __restrict__ wk,
    const float* __restrict__ wv, const float* __restrict__ pj,
    unsigned short* __restrict__ wbuf)
{
    int sel = blockIdx.y;   // 0=wq 1=wk 2=wv 3=proj
    const float* src = sel == 0 ? wq : (sel == 1 ? wk : (sel == 2 ? wv : pj));
    int hi_off = sel == 0 ? 0 : (sel == 1 ? 32768 : (sel == 2 ? WB_V : WB_P));
    int idx = blockIdx.x * 256 + threadIdx.x;     // 0..4095, 4 elems each
    float4 w4 = *(const float4*)(src + idx * 4);
    unsigned short hx = f2bf(w4.x), hy = f2bf(w4.y), hz = f2bf(w4.z), hw = f2bf(w4.w);
    uint2 pk;
    pk.x = hx | ((unsigned)hy << 16); pk.y = hz | ((unsigned)hw << 16);
    *(uint2*)(wbuf + hi_off + idx * 4) = pk;
    if (sel < 2) {
        unsigned short lx = f2bf(w4.x - bf2f(hx)), ly = f2bf(w4.y - bf2f(hy));
        unsigned short lz = f2bf(w4.z - bf2f(hz)), lw = f2bf(w4.w - bf2f(hw));
        pk.x = lx | ((unsigned)ly << 16); pk.y = lz | ((unsigned)lw << 16);
        *(uint2*)(wbuf + hi_off + 16384 + idx * 4) = pk;
    }
}

// ------ depthwise 3x3 (zero-pad SAME), all 3 sels in one pass, out fp32 [sel][c][p] -----
__global__ __launch_bounds__(256) void dw_kernel(
    const float* __restrict__ x,
    const float* __restrict__ wq, const float* __restrict__ wk, const float* __restrict__ wv,
    float* __restrict__ t_dw)
{
    int tid = blockIdx.x * 256 + threadIdx.x;
    int hw = tid % HWS;
    int cf = tid / HWS;
    int c = cf & (CH - 1);
    int tt = cf >> 7;
    int i = hw / WW, j = hw % WW;
    const float* xp = x + (size_t)(tt * CH + c) * HWS;
    float w0[9], w1[9], w2[9];
#pragma unroll
    for (int r = 0; r < 9; r++) { w0[r] = wq[c * 9 + r]; w1[r] = wk[c * 9 + r]; w2[r] = wv[c * 9 + r]; }
    float s0 = 0.f, s1 = 0.f, s2 = 0.f;
#pragma unroll
    for (int r = 0; r < 3; r++) {
        int ii = i + r - 1;
        if (ii < 0 || ii >= HH) continue;
#pragma unroll
        for (int ss = 0; ss < 3; ss++) {
            int jj = j + ss - 1;
            if (jj < 0 || jj >= WW) continue;
            float xv = xp[ii * WW + jj];
            s0 += xv * w0[r * 3 + ss];
            s1 += xv * w1[r * 3 + ss];
            s2 += xv * w2[r * 3 + ss];
        }
    }
    size_t o = (size_t)c * QTOT + tt * HWS + hw;
    t_dw[o] = s0;
    t_dw[QC + o] = s1;
    t_dw[2 * (size_t)QC + o] = s2;
}

// ------ transpose+convert: [c][p] fp32 -> [p][c] bf16; q,k get hi+lo split, v single ----
__global__ __launch_bounds__(256) void transcvt(
    const float* __restrict__ t_dw,
    unsigned short* __restrict__ qk_hi,   // [2][p][c]
    unsigned short* __restrict__ qk_lo,   // [2][p][c]
    unsigned short* __restrict__ v_bf)    // [p][c]
{
    __shared__ float s[64][33];
    int sel = blockIdx.z;
    const float* vd = t_dw + (size_t)sel * QC;
    int t = threadIdx.x;
    int p0 = blockIdx.x * 64;
    int c0 = blockIdx.y * 32;
#pragma unroll
    for (int r = 0; r < 2; r++) {
        int lin = r * 256 + t;
        int c = lin >> 4;
        int pq = lin & 15;
        float4 v4 = *(const float4*)(vd + (size_t)(c0 + c) * QTOT + p0 + pq * 4);
        s[pq * 4 + 0][c] = v4.x; s[pq * 4 + 1][c] = v4.y;
        s[pq * 4 + 2][c] = v4.z; s[pq * 4 + 3][c] = v4.w;
    }
    __syncthreads();
    int p = t >> 2, cq = t & 3;
    unsigned uh[8], ul[8];
#pragma unroll
    for (int j = 0; j < 8; j++) {
        float x = s[p][cq * 8 + j];
        unsigned short h = f2bf(x);
        uh[j] = h;
        ul[j] = f2bf(x - bf2f(h));
    }
    uint4 ph, pl;
    ph.x = uh[0] | (uh[1] << 16); ph.y = uh[2] | (uh[3] << 16);
    ph.z = uh[4] | (uh[5] << 16); ph.w = uh[6] | (uh[7] << 16);
    size_t off = (size_t)(p0 + p) * CH + c0 + cq * 8;
    if (sel < 2) {
        pl.x = ul[0] | (ul[1] << 16); pl.y = ul[2] | (ul[3] << 16);
        pl.z = ul[4] | (ul[5] << 16); pl.w = ul[6] | (ul[7] << 16);
        *(uint4*)(qk_hi + (size_t)sel * QC + off) = ph;
        *(uint4*)(qk_lo + (size_t)sel * QC + off) = pl;
    } else {
        *(uint4*)(v_bf + off) = ph;
    }
}

// ------ q,k pointwise via bf16x3 MFMA; W fragments straight from prepped global --------
__global__ __launch_bounds__(256) void qk_mfma(
    const unsigned short* __restrict__ Ahi,   // [2][p][c]
    const unsigned short* __restrict__ Alo,
    const unsigned short* __restrict__ wbuf,
    const float* __restrict__ bq, const float* __restrict__ bk,
    float* __restrict__ t_dw)                 // out: q -> t_dw[0], k -> t_dw[1] ([p][c])
{
    int sel = blockIdx.y;
    const unsigned short* Wh = wbuf + WB_QK(sel);
    const unsigned short* Wl = Wh + 16384;
    const float* bias = sel ? bk : bq;
    float scale = sel ? 1.f : SCALE;
    const unsigned short* ah = Ahi + (size_t)sel * QC;
    const unsigned short* al = Alo + (size_t)sel * QC;
    float* O = t_dw + (size_t)sel * QC;

    int t = threadIdx.x;
    int wv = t >> 6, lane = t & 63;
    int m = lane & 15, quad = lane >> 4;
    int p0 = blockIdx.x * 64;
    int o0 = wv * 32;
    float bb[2];
#pragma unroll
    for (int ot = 0; ot < 2; ot++) bb[ot] = bias[o0 + ot * 16 + m];
    floatx4 acc[4][2];
#pragma unroll
    for (int i = 0; i < 4; i++)
#pragma unroll
        for (int j = 0; j < 2; j++) acc[i][j] = (floatx4){0.f, 0.f, 0.f, 0.f};
#pragma unroll
    for (int kc = 0; kc < 4; kc++) {
        short8 avh[4], avl[4], bh[2], bl[2];
#pragma unroll
        for (int pt = 0; pt < 4; pt++) {
            size_t base = (size_t)(p0 + pt * 16 + m) * CH + kc * 32 + quad * 8;
            avh[pt] = *(const short8*)(ah + base);
            avl[pt] = *(const short8*)(al + base);
        }
#pragma unroll
        for (int ot = 0; ot < 2; ot++) {
            int widx = (o0 + ot * 16 + m) * CH + kc * 32 + quad * 8;
            bh[ot] = *(const short8*)(Wh + widx);
            bl[ot] = *(const short8*)(Wl + widx);
        }
#pragma unroll
        for (int pt = 0; pt < 4; pt++)
#pragma unroll
            for (int ot = 0; ot < 2; ot++) {
                acc[pt][ot] = __builtin_amdgcn_mfma_f32_16x16x32_bf16(avh[pt], bh[ot], acc[pt][ot], 0, 0, 0);
                acc[pt][ot] = __builtin_amdgcn_mfma_f32_16x16x32_bf16(avh[pt], bl[ot], acc[pt][ot], 0, 0, 0);
                acc[pt][ot] = __builtin_amdgcn_mfma_f32_16x16x32_bf16(avl[pt], bh[ot], acc[pt][ot], 0, 0, 0);
            }
    }
#pragma unroll
    for (int pt = 0; pt < 4; pt++)
#pragma unroll
        for (int ot = 0; ot < 2; ot++)
#pragma unroll
            for (int reg = 0; reg < 4; reg++) {
                int p = p0 + pt * 16 + quad * 4 + reg;
                O[(size_t)p * CH + o0 + ot * 16 + m] = (acc[pt][ot][reg] + bb[ot]) * scale;
            }
}

// ---------------- v pointwise via bf16 MFMA, W from prepped global ----------------
__global__ __launch_bounds__(256) void vgemm_mfma(
    const unsigned short* __restrict__ A,   // v_bf [p][c] bf16
    const unsigned short* __restrict__ wbuf,
    const float* __restrict__ bias,
    float* __restrict__ O)                  // fp32 [p][c]
{
    const unsigned short* Wv = wbuf + WB_V;
    int t = threadIdx.x;
    int wv = t >> 6, lane = t & 63;
    int m = lane & 15, quad = lane >> 4;
    int p0 = blockIdx.x * 64;
    int o0 = wv * 32;
    float bb[2];
#pragma unroll
    for (int ot = 0; ot < 2; ot++) bb[ot] = bias[o0 + ot * 16 + m];
    floatx4 acc[4][2];
#pragma unroll
    for (int i = 0; i < 4; i++)
#pragma unroll
        for (int j = 0; j < 2; j++) acc[i][j] = (floatx4){0.f, 0.f, 0.f, 0.f};
#pragma unroll
    for (int kc = 0; kc < 4; kc++) {
        short8 a[4], b[2];
#pragma unroll
        for (int pt = 0; pt < 4; pt++)
            a[pt] = *(const short8*)(A + (size_t)(p0 + pt * 16 + m) * CH + kc * 32 + quad * 8);
#pragma unroll
        for (int ot = 0; ot < 2; ot++)
            b[ot] = *(const short8*)(Wv + (o0 + ot * 16 + m) * CH + kc * 32 + quad * 8);
#pragma unroll
        for (int pt = 0; pt < 4; pt++)
#pragma unroll
            for (int ot = 0; ot < 2; ot++)
                acc[pt][ot] = __builtin_amdgcn_mfma_f32_16x16x32_bf16(a[pt], b[ot], acc[pt][ot], 0, 0, 0);
    }
#pragma unroll
    for (int pt = 0; pt < 4; pt++)
#pragma unroll
        for (int ot = 0; ot < 2; ot++)
#pragma unroll
            for (int reg = 0; reg < 4; reg++) {
                int p = p0 + pt * 16 + quad * 4 + reg;
                O[(size_t)p * CH + o0 + ot * 16 + m] = acc[pt][ot][reg] + bb[ot];
            }
}

// ------ attention: LDS k-patch, ONE query per wave (16 waves/block), radix select -------
__global__ __launch_bounds__(1024) void attn_kernel(
    const float* __restrict__ q,   // [p][128] fp32
    const float* __restrict__ k,
    const float* __restrict__ v,
    unsigned short* __restrict__ att)  // [p][128] bf16
{
    __shared__ float kp[PR * PC * PSTRIDE];   // 26.5 KB
    int h = blockIdx.y;
    int seg = blockIdx.x;
    int qj0 = (seg % (WW / SEG)) * SEG;
    int qi = (seg / (WW / SEG)) % HH;
    int tt = seg / ((WW / SEG) * HH);
    int t = threadIdx.x;

    // stage reflected k patch: coalesced
#pragma unroll
    for (int r = 0; r < 2; r++) {
        int f = r * 1024 + t;
        if (f < PR * PC * 8) {
            int pix = f >> 3, d4 = f & 7;
            int ci = pix / PC, cj = pix - ci * PC;
            int gi = refl(qi + ci - 4, HH);
            int gj = refl(qj0 + cj - 4, WW);
            int gp = tt * HWS + gi * WW + gj;
            *(float4*)(&kp[pix * PSTRIDE + d4 * 4]) =
                *(const float4*)(k + (size_t)gp * CH + h * HD + d4 * 4);
        }
    }
    __syncthreads();

    int lane = t & 63;
    int ql = __builtin_amdgcn_readfirstlane(t >> 6);   // wave-uniform query index
    int ci = lane >> 3, cjo = lane & 7;
    int di = ci - 4, dj = cjo - 4;
    const int d = lane & (HD - 1);
    const unsigned long long below = (1ull << lane) - 1ull;

    int qj = qj0 + ql;
    int p = tt * HWS + qi * WW + qj;
    const float* qp = q + (size_t)p * CH + h * HD;     // uniform -> s_load
    const float* kr = &kp[(ci * PC + ql + cjo) * PSTRIDE];
    float dist = 0.f;
#pragma unroll
    for (int dd = 0; dd < 8; dd++) {
        float4 qv = *(const float4*)(qp + dd * 4);
        float4 kv = *(const float4*)(kr + dd * 4);
        dist += qv.x * kv.x + qv.y * kv.y + qv.z * kv.z + qv.w * kv.w;
    }
    int cpix = tt * HWS + refl(qi + di, HH) * WW + refl(qj + dj, WW);

    // order-preserving uint key (desc select)
    unsigned u = __float_as_uint(dist);
    unsigned key = (u & 0x80000000u) ? ~u : (u | 0x80000000u);

    // fixed-32 branch-free radix select of the 16th-largest key
    unsigned prefix = 0u;
    int need = KTOP;
#pragma unroll
    for (int bit = 31; bit >= 0; --bit) {
        unsigned hi = (prefix >> bit) | 1u;
        unsigned long long b = __ballot((key >> bit) == hi);
        int cnt = __popcll(b);
        bool take = cnt >= need;
        prefix = take ? (prefix | (1u << bit)) : prefix;
        need = take ? need : need - cnt;
    }
    // selection set: key > kth, plus first `need` of tie class by lane asc
    bool isEq = (key == prefix);
    unsigned long long eqm = __ballot(isEq);
    int rk = __popcll(eqm & below);
    bool selb = (key > prefix) || (isEq && rk < need);
    unsigned long long selm = __ballot(selb);

    // softmax without shift: dists are O(1e-3), exp is exact-safe
    float e = selb ? __expf(dist) : 0.f;

    // walk 16 selected lanes: scalar ctz + readlane, broadcast v rows
    float acc = 0.f, denom = 0.f;
    unsigned long long m0 = selm;
#pragma unroll
    for (int r = 0; r < KTOP; r++) {
        int s0 = __builtin_ctzll(m0); m0 &= m0 - 1ull;
        float a0 = __uint_as_float((unsigned)__builtin_amdgcn_readlane((int)__float_as_uint(e), s0));
        int pr = __builtin_amdgcn_readlane(cpix, s0);
        denom += a0;
        acc += a0 * v[(size_t)pr * CH + h * HD + d];
    }
    if (lane < HD)
        att[(size_t)p * CH + h * HD + lane] = f2bf(acc / denom);
}

// ---------------- proj via bf16 MFMA, W from prepped global ----------------
__global__ __launch_bounds__(256) void proj_mfma(
    const unsigned short* __restrict__ A,   // att_bf [p][c] bf16
    const unsigned short* __restrict__ wbuf,
    const float* __restrict__ bias,
    float* __restrict__ out)                // NCHW fp32
{
    const unsigned short* Wp = wbuf + WB_P;
    int t = threadIdx.x;
    int wv = t >> 6, lane = t & 63;
    int m = lane & 15, quad = lane >> 4;
    int p0 = blockIdx.x * 64;
    int o0 = wv * 32;
    float bb[2][4];
#pragma unroll
    for (int ot = 0; ot < 2; ot++)
#pragma unroll
        for (int reg = 0; reg < 4; reg++) bb[ot][reg] = bias[o0 + ot * 16 + quad * 4 + reg];
    floatx4 acc[2][4];
#pragma unroll
    for (int i = 0; i < 2; i++)
#pragma unroll
        for (int j = 0; j < 4; j++) acc[i][j] = (floatx4){0.f, 0.f, 0.f, 0.f};
#pragma unroll
    for (int kc = 0; kc < 4; kc++) {
        short8 a[2], b[4];
#pragma unroll
        for (int ot = 0; ot < 2; ot++)
            a[ot] = *(const short8*)(Wp + (o0 + ot * 16 + m) * CH + kc * 32 + quad * 8);
#pragma unroll
        for (int pt = 0; pt < 4; pt++)
            b[pt] = *(const short8*)(A + (size_t)(p0 + pt * 16 + m) * CH + kc * 32 + quad * 8);
#pragma unroll
        for (int ot = 0; ot < 2; ot++)
#pragma unroll
            for (int pt = 0; pt < 4; pt++)
                acc[ot][pt] = __builtin_amdgcn_mfma_f32_16x16x32_bf16(a[ot], b[pt], acc[ot][pt], 0, 0, 0);
    }
    int tt = p0 / HWS;
    int hwb = p0 - tt * HWS;
#pragma unroll
    for (int ot = 0; ot < 2; ot++)
#pragma unroll
        for (int pt = 0; pt < 4; pt++)
#pragma unroll
            for (int reg = 0; reg < 4; reg++) {
                int o = o0 + ot * 16 + quad * 4 + reg;
                int hw = hwb + pt * 16 + m;
                out[((size_t)(tt * CH + o)) * HWS + hw] = acc[ot][pt][reg] + bb[ot][reg];
            }
}

extern "C" void kernel_launch(void* const* d_in, const int* in_sizes, int n_in,
                              void* d_out, int out_size, void* d_ws, size_t ws_size,
                              hipStream_t stream) {
    const float* vid    = (const float*)d_in[0];
    const float* wq_dw  = (const float*)d_in[1];
    const float* wq_pw  = (const float*)d_in[2];
    const float* bq     = (const float*)d_in[3];
    const float* wk_dw  = (const float*)d_in[4];
    const float* wk_pw  = (const float*)d_in[5];
    const float* bk     = (const float*)d_in[6];
    const float* wv_dw  = (const float*)d_in[7];
    const float* wv_pw  = (const float*)d_in[8];
    const float* bv     = (const float*)d_in[9];
    const float* proj_w = (const float*)d_in[10];
    const float* proj_b = (const float*)d_in[11];
    float* out = (float*)d_out;

    // workspace (~61.5 MB):
    //   t_dw  : 3*QC fp32 [sel][c][p]; q,k fp32 [p][c] outputs OVERWRITE [0],[1]
    //   v_f32 : QC fp32 [p][c]
    //   qk_hi : 2*QC bf16, qk_lo : 2*QC bf16
    //   v_bf  : QC bf16 (aliased as att_bf after vgemm consumes it)
    //   wbuf  : 98304 bf16 converted weights
    float* t_dw = (float*)d_ws;
    float* v_f32 = t_dw + (size_t)3 * QC;
    unsigned short* qk_hi = (unsigned short*)(v_f32 + (size_t)QC);
    unsigned short* qk_lo = qk_hi + (size_t)2 * QC;
    unsigned short* v_bf = qk_lo + (size_t)2 * QC;
    unsigned short* wbuf = v_bf + (size_t)QC;
    unsigned short* att_bf = v_bf;

    wprep<<<dim3(16, 4), 256, 0, stream>>>(wq_pw, wk_pw, wv_pw, proj_w, wbuf);
    dw_kernel<<<QTOT * CH / 256, 256, 0, stream>>>(vid, wq_dw, wk_dw, wv_dw, t_dw);
    transcvt<<<dim3(QTOT / 64, 4, 3), 256, 0, stream>>>(t_dw, qk_hi, qk_lo, v_bf);
    qk_mfma<<<dim3(QTOT / 64, 2), 256, 0, stream>>>(qk_hi, qk_lo, wbuf, bq, bk, t_dw);
    vgemm_mfma<<<QTOT / 64, 256, 0, stream>>>(v_bf, wbuf, bv, v_f32);
    attn_kernel<<<dim3(TT * HH * (WW / SEG), 4), 1024, 0, stream>>>(
        t_dw, t_dw + (size_t)QC, v_f32, att_bf);
    proj_mfma<<<QTOT / 64, 256, 0, stream>>>(att_bf, wbuf, proj_b, out);
}

// Round 8
// 206.004 us; speedup vs baseline: 1.0418x; 1.0418x over previous
//
#include <hip/hip_runtime.h>
#include <math.h>

#define TT 2
#define CH 128
#define HH 96
#define WW 96
#define HWS 9216            // H*W
#define QTOT 18432          // T*H*W
#define QC (QTOT*CH)
#define HD 32
#define KTOP 16
#define SCALE 0.17677669529663687f  // 32^-0.5

#define SEG 16              // queries per attn block (one row segment)
#define PR 8                // patch rows
#define PC 23               // patch cols
#define PSTRIDE 36          // floats per patch pixel in LDS

typedef __attribute__((ext_vector_type(8))) short short8;
typedef __attribute__((ext_vector_type(4))) float floatx4;

__device__ __forceinline__ unsigned short f2bf(float f) {
    union { float f; unsigned u; } x; x.f = f;
    unsigned r = x.u + 0x7fffu + ((x.u >> 16) & 1u);
    return (unsigned short)(r >> 16);
}
__device__ __forceinline__ float bf2f(unsigned short h) {
    return __uint_as_float(((unsigned)h) << 16);
}

__device__ __forceinline__ int refl(int x, int n) {
    x = x < 0 ? -x : x;
    return x >= n ? 2 * (n - 1) - x : x;
}

// ------ FUSED depthwise 3x3 + bf16 convert: vid -> qk_hi/lo, v_bf, all [p][c] ---------
// lane = pixel (taps coalesced); wave-uniform 8-channel group (weights -> s_load).
// fp32 accumulation order identical to the previous dw_kernel -> bit-identical outputs.
__global__ __launch_bounds__(256) void dwcvt_kernel(
    const float* __restrict__ x,
    const float* __restrict__ wq, const float* __restrict__ wk, const float* __restrict__ wv,
    unsigned short* __restrict__ qk_hi,   // [2][p][c]
    unsigned short* __restrict__ qk_lo,   // [2][p][c]
    unsigned short* __restrict__ v_bf)    // [p][c]
{
    int t = threadIdx.x;
    int pl = t & 63;
    int cg = __builtin_amdgcn_readfirstlane(t >> 6);   // wave-uniform channel group
    int p  = blockIdx.x * 64 + pl;
    int c0 = blockIdx.y * 32 + cg * 8;
    int hw = p % HWS;
    int tt = p / HWS;
    int i = hw / WW, j = hw % WW;

    unsigned qh[4], ql[4], kh[4], kl[4], vh[4];
#pragma unroll
    for (int ic = 0; ic < 8; ic += 2) {
        float sv[3][2];
#pragma unroll
        for (int u = 0; u < 2; u++) {
            int c = c0 + ic + u;
            const float* xp = x + (size_t)(tt * CH + c) * HWS;
            float w0[9], w1[9], w2[9];
#pragma unroll
            for (int r = 0; r < 9; r++) {
                w0[r] = wq[c * 9 + r]; w1[r] = wk[c * 9 + r]; w2[r] = wv[c * 9 + r];
            }
            float s0 = 0.f, s1 = 0.f, s2 = 0.f;
#pragma unroll
            for (int r = 0; r < 3; r++) {
                int ii = i + r - 1;
                if (ii < 0 || ii >= HH) continue;
#pragma unroll
                for (int ss = 0; ss < 3; ss++) {
                    int jj = j + ss - 1;
                    if (jj < 0 || jj >= WW) continue;
                    float xv = xp[ii * WW + jj];
                    s0 += xv * w0[r * 3 + ss];
                    s1 += xv * w1[r * 3 + ss];
                    s2 += xv * w2[r * 3 + ss];
                }
            }
            sv[0][u] = s0; sv[1][u] = s1; sv[2][u] = s2;
        }
        int w = ic >> 1;
        unsigned short h0 = f2bf(sv[0][0]), h1 = f2bf(sv[0][1]);
        qh[w] = h0 | ((unsigned)h1 << 16);
        ql[w] = f2bf(sv[0][0] - bf2f(h0)) | ((unsigned)f2bf(sv[0][1] - bf2f(h1)) << 16);
        h0 = f2bf(sv[1][0]); h1 = f2bf(sv[1][1]);
        kh[w] = h0 | ((unsigned)h1 << 16);
        kl[w] = f2bf(sv[1][0] - bf2f(h0)) | ((unsigned)f2bf(sv[1][1] - bf2f(h1)) << 16);
        vh[w] = f2bf(sv[2][0]) | ((unsigned)f2bf(sv[2][1]) << 16);
    }
    size_t off = (size_t)p * CH + c0;
    uint4 pk;
    pk.x = qh[0]; pk.y = qh[1]; pk.z = qh[2]; pk.w = qh[3];
    *(uint4*)(qk_hi + off) = pk;
    pk.x = ql[0]; pk.y = ql[1]; pk.z = ql[2]; pk.w = ql[3];
    *(uint4*)(qk_lo + off) = pk;
    pk.x = kh[0]; pk.y = kh[1]; pk.z = kh[2]; pk.w = kh[3];
    *(uint4*)(qk_hi + (size_t)QC + off) = pk;
    pk.x = kl[0]; pk.y = kl[1]; pk.z = kl[2]; pk.w = kl[3];
    *(uint4*)(qk_lo + (size_t)QC + off) = pk;
    pk.x = vh[0]; pk.y = vh[1]; pk.z = vh[2]; pk.w = vh[3];
    *(uint4*)(v_bf + off) = pk;
}

// ------ q,k pointwise via bf16x3 MFMA (fp32-emulating split): O = (A W^T + b) * scale ---
__global__ __launch_bounds__(256) void qk_mfma(
    const unsigned short* __restrict__ Ahi,   // [2][p][c]
    const unsigned short* __restrict__ Alo,
    const float* __restrict__ wq_pw, const float* __restrict__ wk_pw,
    const float* __restrict__ bq, const float* __restrict__ bk,
    float* __restrict__ qkf)                  // out: q -> qkf[0], k -> qkf[1] ([p][c])
{
    int sel = blockIdx.y;
    const float* W = sel ? wk_pw : wq_pw;
    const float* bias = sel ? bk : bq;
    float scale = sel ? 1.f : SCALE;
    const unsigned short* ah = Ahi + (size_t)sel * QC;
    const unsigned short* al = Alo + (size_t)sel * QC;
    float* O = qkf + (size_t)sel * QC;

    __shared__ unsigned short Wh[128 * 136];
    __shared__ unsigned short Wl[128 * 136];
    int t = threadIdx.x;
#pragma unroll
    for (int r = 0; r < 16; r++) {
        int lin = r * 256 + t;
        int o = lin >> 5, cq = lin & 31;
        float4 w4 = *(const float4*)(W + o * CH + cq * 4);
        unsigned short hx = f2bf(w4.x), hy = f2bf(w4.y), hz = f2bf(w4.z), hw = f2bf(w4.w);
        unsigned short lx = f2bf(w4.x - bf2f(hx)), ly = f2bf(w4.y - bf2f(hy));
        unsigned short lz = f2bf(w4.z - bf2f(hz)), lw = f2bf(w4.w - bf2f(hw));
        uint2 pk;
        pk.x = hx | ((unsigned)hy << 16); pk.y = hz | ((unsigned)hw << 16);
        *(uint2*)(&Wh[o * 136 + cq * 4]) = pk;
        pk.x = lx | ((unsigned)ly << 16); pk.y = lz | ((unsigned)lw << 16);
        *(uint2*)(&Wl[o * 136 + cq * 4]) = pk;
    }
    __syncthreads();
    int wv = t >> 6, lane = t & 63;
    int m = lane & 15, quad = lane >> 4;
    int p0 = blockIdx.x * 64;
    int o0 = wv * 32;
    float bb[2];
#pragma unroll
    for (int ot = 0; ot < 2; ot++) bb[ot] = bias[o0 + ot * 16 + m];
    floatx4 acc[4][2];
#pragma unroll
    for (int i = 0; i < 4; i++)
#pragma unroll
        for (int j = 0; j < 2; j++) acc[i][j] = (floatx4){0.f, 0.f, 0.f, 0.f};
#pragma unroll
    for (int kc = 0; kc < 4; kc++) {
        short8 avh[4], avl[4], bh[2], bl[2];
#pragma unroll
        for (int pt = 0; pt < 4; pt++) {
            size_t base = (size_t)(p0 + pt * 16 + m) * CH + kc * 32 + quad * 8;
            avh[pt] = *(const short8*)(ah + base);
            avl[pt] = *(const short8*)(al + base);
        }
#pragma unroll
        for (int ot = 0; ot < 2; ot++) {
            int lidx = (o0 + ot * 16 + m) * 136 + kc * 32 + quad * 8;
            bh[ot] = *(const short8*)(&Wh[lidx]);
            bl[ot] = *(const short8*)(&Wl[lidx]);
        }
#pragma unroll
        for (int pt = 0; pt < 4; pt++)
#pragma unroll
            for (int ot = 0; ot < 2; ot++) {
                acc[pt][ot] = __builtin_amdgcn_mfma_f32_16x16x32_bf16(avh[pt], bh[ot], acc[pt][ot], 0, 0, 0);
                acc[pt][ot] = __builtin_amdgcn_mfma_f32_16x16x32_bf16(avh[pt], bl[ot], acc[pt][ot], 0, 0, 0);
                acc[pt][ot] = __builtin_amdgcn_mfma_f32_16x16x32_bf16(avl[pt], bh[ot], acc[pt][ot], 0, 0, 0);
            }
    }
#pragma unroll
    for (int pt = 0; pt < 4; pt++)
#pragma unroll
        for (int ot = 0; ot < 2; ot++)
#pragma unroll
            for (int reg = 0; reg < 4; reg++) {
                int p = p0 + pt * 16 + quad * 4 + reg;
                O[(size_t)p * CH + o0 + ot * 16 + m] = (acc[pt][ot][reg] + bb[ot]) * scale;
            }
}

// ---------------- v pointwise via bf16 MFMA (64-px blocks) ----------------
__global__ __launch_bounds__(256) void vgemm_mfma(
    const unsigned short* __restrict__ A,   // v_bf [p][c] bf16
    const float* __restrict__ W,            // [o][c] fp32
    const float* __restrict__ bias,
    float* __restrict__ O)                  // fp32 [p][c]
{
    __shared__ unsigned short Ws[128 * 136];
    int t = threadIdx.x;
#pragma unroll
    for (int r = 0; r < 16; r++) {
        int lin = r * 256 + t;
        int o = lin >> 5, cq = lin & 31;
        float4 w4 = *(const float4*)(W + o * CH + cq * 4);
        uint2 pk;
        pk.x = f2bf(w4.x) | ((unsigned)f2bf(w4.y) << 16);
        pk.y = f2bf(w4.z) | ((unsigned)f2bf(w4.w) << 16);
        *(uint2*)(&Ws[o * 136 + cq * 4]) = pk;
    }
    __syncthreads();
    int wv = t >> 6, lane = t & 63;
    int m = lane & 15, quad = lane >> 4;
    int p0 = blockIdx.x * 64;
    int o0 = wv * 32;
    float bb[2];
#pragma unroll
    for (int ot = 0; ot < 2; ot++) bb[ot] = bias[o0 + ot * 16 + m];
    floatx4 acc[4][2];
#pragma unroll
    for (int i = 0; i < 4; i++)
#pragma unroll
        for (int j = 0; j < 2; j++) acc[i][j] = (floatx4){0.f, 0.f, 0.f, 0.f};
#pragma unroll
    for (int kc = 0; kc < 4; kc++) {
        short8 a[4], b[2];
#pragma unroll
        for (int pt = 0; pt < 4; pt++)
            a[pt] = *(const short8*)(A + (size_t)(p0 + pt * 16 + m) * CH + kc * 32 + quad * 8);
#pragma unroll
        for (int ot = 0; ot < 2; ot++)
            b[ot] = *(const short8*)(&Ws[(o0 + ot * 16 + m) * 136 + kc * 32 + quad * 8]);
#pragma unroll
        for (int pt = 0; pt < 4; pt++)
#pragma unroll
            for (int ot = 0; ot < 2; ot++)
                acc[pt][ot] = __builtin_amdgcn_mfma_f32_16x16x32_bf16(a[pt], b[ot], acc[pt][ot], 0, 0, 0);
    }
#pragma unroll
    for (int pt = 0; pt < 4; pt++)
#pragma unroll
        for (int ot = 0; ot < 2; ot++)
#pragma unroll
            for (int reg = 0; reg < 4; reg++) {
                int p = p0 + pt * 16 + quad * 4 + reg;
                O[(size_t)p * CH + o0 + ot * 16 + m] = acc[pt][ot][reg] + bb[ot];
            }
}

// ---------------- attention: LDS k-patch + fixed-32 unrolled radix select -------------
__global__ __launch_bounds__(256) void attn_kernel(
    const float* __restrict__ q,   // [p][128] fp32
    const float* __restrict__ k,
    const float* __restrict__ v,
    unsigned short* __restrict__ att)  // [p][128] bf16
{
    __shared__ float kp[PR * PC * PSTRIDE];   // 26.5 KB
    int h = blockIdx.y;
    int seg = blockIdx.x;
    int qj0 = (seg % (WW / SEG)) * SEG;
    int qi = (seg / (WW / SEG)) % HH;
    int tt = seg / ((WW / SEG) * HH);
    int t = threadIdx.x;

    // stage reflected k patch: coalesced
#pragma unroll
    for (int r = 0; r < 6; r++) {
        int f = r * 256 + t;
        if (f < PR * PC * 8) {
            int pix = f >> 3, d4 = f & 7;
            int ci = pix / PC, cj = pix - ci * PC;
            int gi = refl(qi + ci - 4, HH);
            int gj = refl(qj0 + cj - 4, WW);
            int gp = tt * HWS + gi * WW + gj;
            *(float4*)(&kp[pix * PSTRIDE + d4 * 4]) =
                *(const float4*)(k + (size_t)gp * CH + h * HD + d4 * 4);
        }
    }
    __syncthreads();

    int wv = t >> 6, lane = t & 63;
    int ci = lane >> 3, cjo = lane & 7;
    int di = ci - 4, dj = cjo - 4;
    int rowoff = tt * HWS + refl(qi + di, HH) * WW;
    const int d = lane & (HD - 1);
    const unsigned long long below = (1ull << lane) - 1ull;

    for (int ql = wv * 4; ql < wv * 4 + 4; ql++) {
        int qj = qj0 + ql;
        int p = tt * HWS + qi * WW + qj;
        const float* qp = q + (size_t)p * CH + h * HD;
        const float* kr = &kp[(ci * PC + ql + cjo) * PSTRIDE];
        float dist = 0.f;
#pragma unroll
        for (int dd = 0; dd < 8; dd++) {
            float4 qv = *(const float4*)(qp + dd * 4);
            float4 kv = *(const float4*)(kr + dd * 4);
            dist += qv.x * kv.x + qv.y * kv.y + qv.z * kv.z + qv.w * kv.w;
        }
        int cpix = rowoff + refl(qj + dj, WW);

        // order-preserving uint key (desc select)
        unsigned u = __float_as_uint(dist);
        unsigned key = (u & 0x80000000u) ? ~u : (u | 0x80000000u);

        // fixed-32 branch-free radix select of the 16th-largest key
        unsigned prefix = 0u;
        int need = KTOP;
#pragma unroll
        for (int bit = 31; bit >= 0; --bit) {
            unsigned hi = (prefix >> bit) | 1u;
            unsigned long long b = __ballot((key >> bit) == hi);
            int cnt = __popcll(b);
            bool take = cnt >= need;
            prefix = take ? (prefix | (1u << bit)) : prefix;
            need = take ? need : need - cnt;
        }
        // selection set: key > kth, plus first `need` of tie class by lane asc
        bool isEq = (key == prefix);
        unsigned long long eqm = __ballot(isEq);
        int rk = __popcll(eqm & below);
        bool selb = (key > prefix) || (isEq && rk < need);
        unsigned long long selm = __ballot(selb);

        // softmax without shift: dists are O(1e-3), exp is exact-safe
        float e = selb ? __expf(dist) : 0.f;

        // walk 16 selected lanes: scalar ctz + readlane, broadcast v rows
        float acc = 0.f, denom = 0.f;
        unsigned long long m0 = selm;
#pragma unroll
        for (int r = 0; r < KTOP; r++) {
            int s0 = __builtin_ctzll(m0); m0 &= m0 - 1ull;
            float a0 = __uint_as_float((unsigned)__builtin_amdgcn_readlane((int)__float_as_uint(e), s0));
            int p0 = __builtin_amdgcn_readlane(cpix, s0);
            denom += a0;
            acc += a0 * v[(size_t)p0 * CH + h * HD + d];
        }
        if (lane < HD)
            att[(size_t)p * CH + h * HD + lane] = f2bf(acc / denom);
    }
}

// ---------------- proj via bf16 MFMA (64-px blocks) ----------------
__global__ __launch_bounds__(256) void proj_mfma(
    const unsigned short* __restrict__ A,   // att_bf [p][c] bf16
    const float* __restrict__ W,            // proj_w [o][c] fp32
    const float* __restrict__ bias,
    float* __restrict__ out)                // NCHW fp32
{
    __shared__ unsigned short Ws[128 * 136];
    int t = threadIdx.x;
#pragma unroll
    for (int r = 0; r < 16; r++) {
        int lin = r * 256 + t;
        int o = lin >> 5, cq = lin & 31;
        float4 w4 = *(const float4*)(W + o * CH + cq * 4);
        uint2 pk;
        pk.x = f2bf(w4.x) | ((unsigned)f2bf(w4.y) << 16);
        pk.y = f2bf(w4.z) | ((unsigned)f2bf(w4.w) << 16);
        *(uint2*)(&Ws[o * 136 + cq * 4]) = pk;
    }
    __syncthreads();
    int wv = t >> 6, lane = t & 63;
    int m = lane & 15, quad = lane >> 4;
    int p0 = blockIdx.x * 64;
    int o0 = wv * 32;
    float bb[2][4];
#pragma unroll
    for (int ot = 0; ot < 2; ot++)
#pragma unroll
        for (int reg = 0; reg < 4; reg++) bb[ot][reg] = bias[o0 + ot * 16 + quad * 4 + reg];
    floatx4 acc[2][4];
#pragma unroll
    for (int i = 0; i < 2; i++)
#pragma unroll
        for (int j = 0; j < 4; j++) acc[i][j] = (floatx4){0.f, 0.f, 0.f, 0.f};
#pragma unroll
    for (int kc = 0; kc < 4; kc++) {
        short8 a[2], b[4];
#pragma unroll
        for (int ot = 0; ot < 2; ot++)
            a[ot] = *(const short8*)(&Ws[(o0 + ot * 16 + m) * 136 + kc * 32 + quad * 8]);
#pragma unroll
        for (int pt = 0; pt < 4; pt++)
            b[pt] = *(const short8*)(A + (size_t)(p0 + pt * 16 + m) * CH + kc * 32 + quad * 8);
#pragma unroll
        for (int ot = 0; ot < 2; ot++)
#pragma unroll
            for (int pt = 0; pt < 4; pt++)
                acc[ot][pt] = __builtin_amdgcn_mfma_f32_16x16x32_bf16(a[ot], b[pt], acc[ot][pt], 0, 0, 0);
    }
    int tt = p0 / HWS;
    int hwb = p0 - tt * HWS;
#pragma unroll
    for (int ot = 0; ot < 2; ot++)
#pragma unroll
        for (int pt = 0; pt < 4; pt++)
#pragma unroll
            for (int reg = 0; reg < 4; reg++) {
                int o = o0 + ot * 16 + quad * 4 + reg;
                int hw = hwb + pt * 16 + m;
                out[((size_t)(tt * CH + o)) * HWS + hw] = acc[ot][pt][reg] + bb[ot][reg];
            }
}

extern "C" void kernel_launch(void* const* d_in, const int* in_sizes, int n_in,
                              void* d_out, int out_size, void* d_ws, size_t ws_size,
                              hipStream_t stream) {
    const float* vid    = (const float*)d_in[0];
    const float* wq_dw  = (const float*)d_in[1];
    const float* wq_pw  = (const float*)d_in[2];
    const float* bq     = (const float*)d_in[3];
    const float* wk_dw  = (const float*)d_in[4];
    const float* wk_pw  = (const float*)d_in[5];
    const float* bk     = (const float*)d_in[6];
    const float* wv_dw  = (const float*)d_in[7];
    const float* wv_pw  = (const float*)d_in[8];
    const float* bv     = (const float*)d_in[9];
    const float* proj_w = (const float*)d_in[10];
    const float* proj_b = (const float*)d_in[11];
    float* out = (float*)d_out;

    // workspace (~52 MB):
    //   qkf   : 2*QC fp32 [p][c]   (q,k after pointwise; attn input)
    //   v_f32 : QC fp32 [p][c]
    //   qk_hi : 2*QC bf16, qk_lo : 2*QC bf16   (dwcvt outputs)
    //   v_bf  : QC bf16 (aliased as att_bf after vgemm consumes it)
    float* qkf = (float*)d_ws;
    float* v_f32 = qkf + (size_t)2 * QC;
    unsigned short* qk_hi = (unsigned short*)(v_f32 + (size_t)QC);
    unsigned short* qk_lo = qk_hi + (size_t)2 * QC;
    unsigned short* v_bf = qk_lo + (size_t)2 * QC;
    unsigned short* att_bf = v_bf;

    dwcvt_kernel<<<dim3(QTOT / 64, 4), 256, 0, stream>>>(
        vid, wq_dw, wk_dw, wv_dw, qk_hi, qk_lo, v_bf);
    qk_mfma<<<dim3(QTOT / 64, 2), 256, 0, stream>>>(qk_hi, qk_lo, wq_pw, wk_pw, bq, bk, qkf);
    vgemm_mfma<<<QTOT / 64, 256, 0, stream>>>(v_bf, wv_pw, bv, v_f32);
    attn_kernel<<<dim3(TT * HH * (WW / SEG), 4), 256, 0, stream>>>(
        qkf, qkf + (size_t)QC, v_f32, att_bf);
    proj_mfma<<<QTOT / 64, 256, 0, stream>>>(att_bf, proj_w, proj_b, out);
}